// Round 2
// baseline (1196.124 us; speedup 1.0000x reference)
//
#include <hip/hip_runtime.h>
#include <hip/hip_bf16.h>

// ---------------------------------------------------------------------------
// STGCN: conv_glu -> gcn_relu -> conv_glu -> conv_glu -> gcn_relu -> gap -> conv_glu
// N=50000 nodes, E=500000 edges, G=16 graphs, C_IN=2, CO_T=64, CO_S=16, K=3
// Strategy: fuse every 64-channel stage with the following 64->16 projection so
// only 16-channel tensors (xw1: N x 10 x 16, xw2: N x 6 x 16) hit HBM.
// ---------------------------------------------------------------------------

#define NN 50000
#define NE 500000
#define NG 16

__device__ __forceinline__ float sigf(float g) {
    return 1.0f / (1.0f + __expf(-g));
}

// ---- degree / dinv --------------------------------------------------------
__global__ void k_deg(const int* __restrict__ col, float* __restrict__ deg, int E) {
    int e = blockIdx.x * 256 + threadIdx.x;
    if (e < E) atomicAdd(&deg[col[e]], 1.0f);
}

__global__ void k_dinv(const float* __restrict__ deg, float* __restrict__ dinv, int n) {
    int i = blockIdx.x * 256 + threadIdx.x;
    if (i < n) dinv[i] = rsqrtf(deg[i] + 1.0f);
}

// ---- conv_glu1 (2->64, T 12->10) fused with 64->16 projection -------------
// thread = (node, t_out). Output layout xw1[n][t][d], d fastest.
__global__ __launch_bounds__(256) void k_conv1_proj(
    const float* __restrict__ x, const float* __restrict__ w,
    const float* __restrict__ b, const float* __restrict__ W1,
    float* __restrict__ xw1, int nNodes)
{
    __shared__ float ws[768];   // w_t1a (128,2,3)
    __shared__ float bs[128];
    __shared__ float W1s[1024]; // w_s1 (64,16)
    int tid = threadIdx.x;
    for (int i = tid; i < 768;  i += 256) ws[i]  = w[i];
    for (int i = tid; i < 1024; i += 256) W1s[i] = W1[i];
    if (tid < 128) bs[tid] = b[tid];
    __syncthreads();

    int idx = blockIdx.x * 256 + tid;
    if (idx >= nNodes * 10) return;
    int n = idx / 10, t = idx % 10;

    float xr[6];
#pragma unroll
    for (int ci = 0; ci < 2; ++ci)
#pragma unroll
        for (int k = 0; k < 3; ++k)
            xr[ci * 3 + k] = x[n * 24 + ci * 12 + t + k];

    float acc[16];
#pragma unroll
    for (int d = 0; d < 16; ++d) acc[d] = 0.f;

    for (int c = 0; c < 64; ++c) {
        float a = bs[c], g = bs[c + 64];
#pragma unroll
        for (int j = 0; j < 6; ++j) {
            a = fmaf(ws[c * 6 + j],        xr[j], a);
            g = fmaf(ws[(c + 64) * 6 + j], xr[j], g);
        }
        float h = a * sigf(g);
#pragma unroll
        for (int d = 0; d < 16; ++d) acc[d] = fmaf(W1s[c * 16 + d], h, acc[d]);
    }
    float* o = &xw1[n * 160 + t * 16];
#pragma unroll
    for (int d = 0; d < 16; ++d) o[d] = acc[d];
}

// ---- GCN edge scatter: agg[col] += xw[row] * dinv[row]*dinv[col] ----------
// one wave per edge, lanes stride the WIDTH channel*time elements
template <int WIDTH>
__global__ __launch_bounds__(256) void k_scatter(
    const float* __restrict__ xw, const int* __restrict__ row,
    const int* __restrict__ col, const float* __restrict__ dinv,
    float* __restrict__ agg, int E)
{
    int gtid = blockIdx.x * 256 + threadIdx.x;
    int e = gtid >> 6, lane = gtid & 63;
    if (e >= E) return;
    int r = row[e], c = col[e];
    float coef = dinv[r] * dinv[c];
    const float* src = xw  + (size_t)r * WIDTH;
    float*       dst = agg + (size_t)c * WIDTH;
#pragma unroll
    for (int i = lane; i < WIDTH; i += 64)
        atomicAdd(&dst[i], src[i] * coef);
}

// ---- GCN epilogue: h = relu(agg + xw*dinv^2 + bias) (in place on agg) -----
template <int WIDTH>
__global__ __launch_bounds__(256) void k_gcn_finish(
    float* __restrict__ agg, const float* __restrict__ xw,
    const float* __restrict__ dinv, const float* __restrict__ bias, int total)
{
    int i = blockIdx.x * 256 + threadIdx.x;
    if (i >= total) return;
    int n = i / WIDTH;
    float di = dinv[n];
    float v = agg[i] + xw[i] * di * di + bias[i & 15];
    agg[i] = fmaxf(v, 0.f);
}

// ---- conv_glu2 (16->64, 10->8) + conv_glu3 (64->64, 8->6) + proj 64->16 ---
// 512 threads = 8 waves = 8 nodes per block; lane = output channel.
__global__ __launch_bounds__(512) void k_conv23_proj(
    const float* __restrict__ h2, const float* __restrict__ w1b,
    const float* __restrict__ b1b, const float* __restrict__ w2a,
    const float* __restrict__ b2a, const float* __restrict__ ws2,
    float* __restrict__ xw2, int nNodes)
{
    __shared__ float wbuf[128 * 49]; // padded rows (48 -> 49) to kill bank conflicts
    __shared__ float W2s[1024];
    __shared__ float b2s[128];
    __shared__ float b3s[128];
    __shared__ float h2s[8 * 160];   // [wave][t(10)][ci(16)]
    __shared__ float h3s[8 * 768];   // [wave][c(64)][t stride 12]

    int tid = threadIdx.x;
    int base = blockIdx.x * 8;

    for (int i = tid; i < 128 * 48; i += 512) {
        int o = i / 48, j = i % 48;
        wbuf[o * 49 + j] = w1b[i];
    }
    for (int i = tid; i < 1024; i += 512) W2s[i] = ws2[i];
    if (tid < 128) { b2s[tid] = b1b[tid]; b3s[tid] = b2a[tid]; }
    for (int i = tid; i < 8 * 160; i += 512) h2s[i] = h2[(size_t)base * 160 + i];
    __syncthreads();

    int w = tid >> 6, lane = tid & 63;
    const float* h2w = &h2s[w * 160];
    float* h3w = &h3s[w * 768];

    // conv2: (16,10) -> (64,8)
    float a[8], g[8];
#pragma unroll
    for (int t = 0; t < 8; ++t) { a[t] = b2s[lane]; g[t] = b2s[lane + 64]; }
#pragma unroll
    for (int ci = 0; ci < 16; ++ci) {
        float hv[10];
#pragma unroll
        for (int t = 0; t < 10; ++t) hv[t] = h2w[t * 16 + ci];
#pragma unroll
        for (int k = 0; k < 3; ++k) {
            float wa = wbuf[lane * 49 + ci * 3 + k];
            float wg = wbuf[(lane + 64) * 49 + ci * 3 + k];
#pragma unroll
            for (int t = 0; t < 8; ++t) {
                a[t] = fmaf(wa, hv[t + k], a[t]);
                g[t] = fmaf(wg, hv[t + k], g[t]);
            }
        }
    }
#pragma unroll
    for (int t = 0; t < 8; ++t) h3w[lane * 12 + t] = a[t] * sigf(g[t]);

    // conv3: (64,8) -> (64,6), w_t2a streamed through LDS in 4 chunks of 16 ci
    float a4[6], g4[6];
#pragma unroll
    for (int t = 0; t < 6; ++t) { a4[t] = b3s[lane]; g4[t] = b3s[lane + 64]; }

    for (int cc = 0; cc < 4; ++cc) {
        __syncthreads();  // all waves done reading wbuf
        for (int i = tid; i < 128 * 48; i += 512) {
            int o = i / 48, j = i % 48;
            wbuf[o * 49 + j] = w2a[o * 192 + cc * 48 + j];
        }
        __syncthreads();
#pragma unroll
        for (int cil = 0; cil < 16; ++cil) {
            int ci = cc * 16 + cil;
            float hv[8];
#pragma unroll
            for (int t = 0; t < 8; ++t) hv[t] = h3w[ci * 12 + t];
#pragma unroll
            for (int k = 0; k < 3; ++k) {
                float wa = wbuf[lane * 49 + cil * 3 + k];
                float wg = wbuf[(lane + 64) * 49 + cil * 3 + k];
#pragma unroll
                for (int t = 0; t < 6; ++t) {
                    a4[t] = fmaf(wa, hv[t + k], a4[t]);
                    g4[t] = fmaf(wg, hv[t + k], g4[t]);
                }
            }
        }
    }

    // h4 (wave-private overwrite of rows t=0..5 of this lane's channel)
#pragma unroll
    for (int t = 0; t < 6; ++t) h3w[lane * 12 + t] = a4[t] * sigf(g4[t]);

    // projection: xw2[n][t][d] = sum_c h4[c][t] * W2[c][d]
    int node = base + w;
#pragma unroll
    for (int rep = 0; rep < 2; ++rep) {
        int idx = lane + rep * 64;
        if (idx < 96) {
            int d = idx / 6, t = idx % 6;
            float s = 0.f;
#pragma unroll
            for (int c = 0; c < 64; ++c)
                s = fmaf(W2s[c * 16 + d], h3w[c * 12 + t], s);
            xw2[(size_t)node * 96 + t * 16 + d] = s;
        }
    }
}

// ---- counts per graph via binary search (batch is sorted) -----------------
__global__ void k_counts(const int* __restrict__ batch, float* __restrict__ cnt,
                         int n, int ngraphs)
{
    int g = threadIdx.x;
    if (g >= ngraphs) return;
    int lo = 0, hi = n;
    while (lo < hi) { int m = (lo + hi) >> 1; if (batch[m] < g) lo = m + 1; else hi = m; }
    int lo2 = 0, hi2 = n;
    while (lo2 < hi2) { int m = (lo2 + hi2) >> 1; if (batch[m] < g + 1) lo2 = m + 1; else hi2 = m; }
    cnt[g] = (float)(lo2 - lo);
}

// ---- mean-pool numerator: run-length accumulate (batch sorted) ------------
__global__ __launch_bounds__(128) void k_pool(
    const float* __restrict__ h5, const int* __restrict__ batch,
    float* __restrict__ pool, int nNodes)
{
    int j = threadIdx.x;
    if (j >= 96) return;
    int n0 = blockIdx.x * 64;
    int n1 = min(n0 + 64, nNodes);
    int cur = batch[n0];
    float acc = 0.f;
    for (int n = n0; n < n1; ++n) {
        int g = batch[n];
        if (g != cur) { atomicAdd(&pool[cur * 96 + j], acc); acc = 0.f; cur = g; }
        acc += h5[(size_t)n * 96 + j];
    }
    atomicAdd(&pool[cur * 96 + j], acc);
}

// ---- final conv_glu on pooled means: (16,16,6) -> (16,64,4) ---------------
__global__ __launch_bounds__(256) void k_final(
    const float* __restrict__ pool, const float* __restrict__ cnt,
    const float* __restrict__ w, const float* __restrict__ b,
    float* __restrict__ out)
{
    __shared__ float m[96];
    __shared__ float ws[6144];  // w_t2b (128,16,3) -- FULL size (was 768: OOB bug)
    __shared__ float bs[128];
    int g = blockIdx.x, tid = threadIdx.x;
    if (tid < 96) m[tid] = pool[g * 96 + tid] / fmaxf(cnt[g], 1.0f);
    for (int i = tid; i < 6144; i += 256) ws[i] = w[i];
    if (tid < 128) bs[tid] = b[tid];
    __syncthreads();

    int c = tid >> 2, t = tid & 3;
    float a = bs[c], gg = bs[c + 64];
#pragma unroll
    for (int ci = 0; ci < 16; ++ci)
#pragma unroll
        for (int k = 0; k < 3; ++k) {
            float xv = m[(t + k) * 16 + ci];
            a  = fmaf(ws[c * 48 + ci * 3 + k],        xv, a);
            gg = fmaf(ws[(c + 64) * 48 + ci * 3 + k], xv, gg);
        }
    out[g * 256 + c * 4 + t] = a * sigf(gg);
}

// ---------------------------------------------------------------------------
extern "C" void kernel_launch(void* const* d_in, const int* in_sizes, int n_in,
                              void* d_out, int out_size, void* d_ws, size_t ws_size,
                              hipStream_t stream)
{
    const float* x      = (const float*)d_in[0];
    const int*   ei     = (const int*)  d_in[1];   // (2, E): row then col
    const int*   batch  = (const int*)  d_in[2];
    const float* w_t1a  = (const float*)d_in[3];
    const float* b_t1a  = (const float*)d_in[4];
    const float* w_s1   = (const float*)d_in[5];
    const float* bb_s1  = (const float*)d_in[6];
    const float* w_t1b  = (const float*)d_in[7];
    const float* b_t1b  = (const float*)d_in[8];
    const float* w_t2a  = (const float*)d_in[9];
    const float* b_t2a  = (const float*)d_in[10];
    const float* w_s2   = (const float*)d_in[11];
    const float* bb_s2  = (const float*)d_in[12];
    const float* w_t2b  = (const float*)d_in[13];
    const float* b_t2b  = (const float*)d_in[14];
    float* out = (float*)d_out;

    const int* row = ei;
    const int* col = ei + NE;

    // workspace layout (small buffers first; xw/agg regions reused across the
    // two GCN stages to halve the footprint -> ~64.5 MB total)
    float* wsp  = (float*)d_ws;
    float* dinv = wsp;                    // N
    float* deg  = dinv + NN;              // N
    float* pool = deg  + NN;              // 16*96
    float* cnt  = pool + NG * 96;         // 16
    float* xw   = cnt  + NG;              // N*160 (xw1, then xw2 uses first N*96)
    float* agg  = xw   + (size_t)NN * 160;// N*160 (agg1/h2, then agg2/h5 first N*96)

    // zero phase-1 accumulators (stream-ordered, graph-capture-safe)
    hipMemsetAsync(agg,  0, (size_t)NN * 160 * sizeof(float), stream);
    hipMemsetAsync(deg,  0, (size_t)NN * sizeof(float), stream);
    hipMemsetAsync(pool, 0, (size_t)NG * 96 * sizeof(float), stream);

    // degrees
    k_deg <<<(NE + 255) / 256, 256, 0, stream>>>(col, deg, NE);
    k_dinv<<<(NN + 255) / 256, 256, 0, stream>>>(deg, dinv, NN);

    // stage 1: conv_glu1 + proj
    k_conv1_proj<<<(NN * 10 + 255) / 256, 256, 0, stream>>>(
        x, w_t1a, b_t1a, w_s1, xw, NN);

    // GCN 1
    k_scatter<160><<<(NE * 64) / 256, 256, 0, stream>>>(xw, row, col, dinv, agg, NE);
    k_gcn_finish<160><<<((NN * 160) + 255) / 256, 256, 0, stream>>>(
        agg, xw, dinv, bb_s1, NN * 160);

    // stage 2: conv_glu2 + conv_glu3 + proj  (reads agg=h2, writes xw=xw2)
    k_conv23_proj<<<NN / 8, 512, 0, stream>>>(
        agg, w_t1b, b_t1b, w_t2a, b_t2a, w_s2, xw, NN);

    // agg region reused as agg2: zero it AFTER conv23 consumed h2 (stream order)
    hipMemsetAsync(agg, 0, (size_t)NN * 96 * sizeof(float), stream);

    // GCN 2
    k_scatter<96><<<(NE * 64) / 256, 256, 0, stream>>>(xw, row, col, dinv, agg, NE);
    k_gcn_finish<96><<<((NN * 96) + 255) / 256, 256, 0, stream>>>(
        agg, xw, dinv, bb_s2, NN * 96);

    // pooling
    k_counts<<<1, 64, 0, stream>>>(batch, cnt, NN, NG);
    k_pool<<<(NN + 63) / 64, 128, 0, stream>>>(agg, batch, pool, NN);

    // final conv_glu
    k_final<<<NG, 256, 0, stream>>>(pool, cnt, w_t2b, b_t2b, out);
}

// Round 3
// 991.729 us; speedup vs baseline: 1.2061x; 1.2061x over previous
//
#include <hip/hip_runtime.h>
#include <hip/hip_bf16.h>

// ---------------------------------------------------------------------------
// STGCN: conv_glu -> gcn_relu -> conv_glu -> conv_glu -> gcn_relu -> gap -> conv_glu
// N=50000, E=500000, G=16, C_IN=2, CO_T=64, CO_S=16, K=3
// conv23 kernel v2: P=4 node-subgroups per wave, all-b128 LDS traffic,
// packed weight tiles, register-resident h3, quarter-streamed conv3 weights.
// ---------------------------------------------------------------------------

#define NN 50000
#define NE 500000
#define NG 16

__device__ __forceinline__ float sigf(float g) {
    return 1.0f / (1.0f + __expf(-g));
}

// ---- degree / dinv --------------------------------------------------------
__global__ void k_deg(const int* __restrict__ col, float* __restrict__ deg, int E) {
    int e = blockIdx.x * 256 + threadIdx.x;
    if (e < E) atomicAdd(&deg[col[e]], 1.0f);
}

__global__ void k_dinv(const float* __restrict__ deg, float* __restrict__ dinv, int n) {
    int i = blockIdx.x * 256 + threadIdx.x;
    if (i < n) dinv[i] = rsqrtf(deg[i] + 1.0f);
}

// ---- conv_glu1 (2->64, T 12->10) fused with 64->16 projection -------------
__global__ __launch_bounds__(256) void k_conv1_proj(
    const float* __restrict__ x, const float* __restrict__ w,
    const float* __restrict__ b, const float* __restrict__ W1,
    float* __restrict__ xw1, int nNodes)
{
    __shared__ float ws[768];
    __shared__ float bs[128];
    __shared__ float W1s[1024];
    int tid = threadIdx.x;
    for (int i = tid; i < 768;  i += 256) ws[i]  = w[i];
    for (int i = tid; i < 1024; i += 256) W1s[i] = W1[i];
    if (tid < 128) bs[tid] = b[tid];
    __syncthreads();

    int idx = blockIdx.x * 256 + tid;
    if (idx >= nNodes * 10) return;
    int n = idx / 10, t = idx % 10;

    float xr[6];
#pragma unroll
    for (int ci = 0; ci < 2; ++ci)
#pragma unroll
        for (int k = 0; k < 3; ++k)
            xr[ci * 3 + k] = x[n * 24 + ci * 12 + t + k];

    float acc[16];
#pragma unroll
    for (int d = 0; d < 16; ++d) acc[d] = 0.f;

    for (int c = 0; c < 64; ++c) {
        float a = bs[c], g = bs[c + 64];
#pragma unroll
        for (int j = 0; j < 6; ++j) {
            a = fmaf(ws[c * 6 + j],        xr[j], a);
            g = fmaf(ws[(c + 64) * 6 + j], xr[j], g);
        }
        float h = a * sigf(g);
#pragma unroll
        for (int d = 0; d < 16; ++d) acc[d] = fmaf(W1s[c * 16 + d], h, acc[d]);
    }
    float* o = &xw1[n * 160 + t * 16];
#pragma unroll
    for (int d = 0; d < 16; ++d) o[d] = acc[d];
}

// ---- GCN edge scatter -----------------------------------------------------
template <int WIDTH>
__global__ __launch_bounds__(256) void k_scatter(
    const float* __restrict__ xw, const int* __restrict__ row,
    const int* __restrict__ col, const float* __restrict__ dinv,
    float* __restrict__ agg, int E)
{
    int gtid = blockIdx.x * 256 + threadIdx.x;
    int e = gtid >> 6, lane = gtid & 63;
    if (e >= E) return;
    int r = row[e], c = col[e];
    float coef = dinv[r] * dinv[c];
    const float* src = xw  + (size_t)r * WIDTH;
    float*       dst = agg + (size_t)c * WIDTH;
#pragma unroll
    for (int i = lane; i < WIDTH; i += 64)
        atomicAdd(&dst[i], src[i] * coef);
}

// ---- GCN epilogue ---------------------------------------------------------
template <int WIDTH>
__global__ __launch_bounds__(256) void k_gcn_finish(
    float* __restrict__ agg, const float* __restrict__ xw,
    const float* __restrict__ dinv, const float* __restrict__ bias, int total)
{
    int i = blockIdx.x * 256 + threadIdx.x;
    if (i >= total) return;
    int n = i / WIDTH;
    float di = dinv[n];
    float v = agg[i] + xw[i] * di * di + bias[i & 15];
    agg[i] = fmaxf(v, 0.f);
}

// ---------------------------------------------------------------------------
// conv_glu2 (16->64, 10->8) + conv_glu3 (64->64, 8->6) + proj 64->16, v2.
// Block = 256 thr = 4 waves; wave = 4 subgroups x 16 lanes; subgroup = 1 node.
// Lane l16 owns channel slots co = l16+16j (j=0..3), a and g halves.
// All LDS traffic vectorized (b128); conv3 weights streamed per ci-quarter.
// ---------------------------------------------------------------------------
__global__ __launch_bounds__(256) void k_conv23_v2(
    const float* __restrict__ h2g, const float* __restrict__ w1b,
    const float* __restrict__ b1b, const float* __restrict__ w2a,
    const float* __restrict__ b2a, const float* __restrict__ ws2,
    float* __restrict__ xw2)
{
    __shared__ float wbuf[6144];   // packed weights [c4][o(128)][12], 48B units
    __shared__ float h2s[3136];    // [node(16)][ci(16)][t pad12], node stride 196
    __shared__ float h3q[2112];    // quarter buf [node(16)][ci_l(16)][t pad8], stride 132
    __shared__ float W2T[1024];    // [d(16)][co(64)]
    __shared__ float bs2[128];
    __shared__ float bs3[128];

    const int tid    = threadIdx.x;
    const int l16    = tid & 15;
    const int node_l = tid >> 4;          // 0..15
    const int base   = blockIdx.x * 16;   // grid = NN/16 = 3125 exactly

    // ---- stage biases, W2T, packed conv2 weights, transposed h2 ----
    if (tid < 128) { bs2[tid] = b1b[tid]; bs3[tid] = b2a[tid]; }
#pragma unroll 1
    for (int i = tid; i < 1024; i += 256) W2T[i] = ws2[(i & 63) * 16 + (i >> 6)];
#pragma unroll 1
    for (int i = tid; i < 1536; i += 256) {        // w1b: [o(128)][48] -> wbuf
        int unit = i / 3, p = i - unit * 3;
        int c4 = unit >> 7, o = unit & 127;
        float4 v = *(const float4*)&w1b[o * 48 + c4 * 12 + p * 4];
        *(float4*)&wbuf[c4 * 1536 + o * 12 + p * 4] = v;
    }
#pragma unroll 1
    for (int i = tid; i < 640; i += 256) {         // h2 [n][t(10)][ci(16)] -> [ci][t]
        int nl = i / 40, r4 = i - nl * 40;
        int t = r4 >> 2, ci0 = (r4 & 3) << 2;
        float4 v = *(const float4*)&h2g[(size_t)(base + nl) * 160 + t * 16 + ci0];
        h2s[nl * 196 + (ci0 + 0) * 12 + t] = v.x;
        h2s[nl * 196 + (ci0 + 1) * 12 + t] = v.y;
        h2s[nl * 196 + (ci0 + 2) * 12 + t] = v.z;
        h2s[nl * 196 + (ci0 + 3) * 12 + t] = v.w;
    }
    __syncthreads();

    // ---------------- conv2: (16,10) -> (64+64, 8) ----------------
    float acc[8][8];
#pragma unroll
    for (int j = 0; j < 4; ++j) {
        float ba = bs2[l16 + 16 * j];
        float bg = bs2[64 + l16 + 16 * j];
#pragma unroll
        for (int t = 0; t < 8; ++t) { acc[j][t] = ba; acc[j + 4][t] = bg; }
    }

#pragma unroll 1
    for (int c4 = 0; c4 < 4; ++c4) {
        float hv[4][12];
#pragma unroll
        for (int i = 0; i < 4; ++i) {
            const float* hp = &h2s[node_l * 196 + (c4 * 4 + i) * 12];
            float4 v0 = *(const float4*)(hp);
            float4 v1 = *(const float4*)(hp + 4);
            float4 v2 = *(const float4*)(hp + 8);
            hv[i][0] = v0.x; hv[i][1] = v0.y; hv[i][2]  = v0.z; hv[i][3]  = v0.w;
            hv[i][4] = v1.x; hv[i][5] = v1.y; hv[i][6]  = v1.z; hv[i][7]  = v1.w;
            hv[i][8] = v2.x; hv[i][9] = v2.y; hv[i][10] = v2.z; hv[i][11] = v2.w;
        }
#pragma unroll
        for (int j = 0; j < 8; ++j) {
            const int o = (j < 4) ? (l16 + 16 * j) : (64 + l16 + 16 * (j - 4));
            const float* wp = &wbuf[c4 * 1536 + o * 12];
            float4 w0 = *(const float4*)(wp);
            float4 w1 = *(const float4*)(wp + 4);
            float4 w2 = *(const float4*)(wp + 8);
            float wr[12];
            wr[0] = w0.x; wr[1] = w0.y; wr[2]  = w0.z; wr[3]  = w0.w;
            wr[4] = w1.x; wr[5] = w1.y; wr[6]  = w1.z; wr[7]  = w1.w;
            wr[8] = w2.x; wr[9] = w2.y; wr[10] = w2.z; wr[11] = w2.w;
#pragma unroll
            for (int i = 0; i < 4; ++i)
#pragma unroll
                for (int k = 0; k < 3; ++k)
#pragma unroll
                    for (int t = 0; t < 8; ++t)
                        acc[j][t] = fmaf(wr[i * 3 + k], hv[i][t + k], acc[j][t]);
        }
    }

    // GLU -> lane-resident h3 (4 co x 8 t)
    float h3r[4][8];
#pragma unroll
    for (int j = 0; j < 4; ++j)
#pragma unroll
        for (int t = 0; t < 8; ++t)
            h3r[j][t] = acc[j][t] * sigf(acc[j + 4][t]);

    // ---------------- conv3: (64,8) -> (64+64, 6), quarter-streamed ----------
    float acc3[8][6];
#pragma unroll
    for (int j = 0; j < 4; ++j) {
        float ba = bs3[l16 + 16 * j];
        float bg = bs3[64 + l16 + 16 * j];
#pragma unroll
        for (int t = 0; t < 6; ++t) { acc3[j][t] = ba; acc3[j + 4][t] = bg; }
    }

#pragma unroll 1
    for (int q = 0; q < 4; ++q) {
        // compile-time select of h3r[q] (avoid runtime reg-array index)
        float hq8[8];
#pragma unroll
        for (int j = 0; j < 4; ++j)
            if (q == j) {
#pragma unroll
                for (int t = 0; t < 8; ++t) hq8[t] = h3r[j][t];
            }

        __syncthreads();  // prior readers of h3q/wbuf done
        {   // each lane writes its co = l16+16q slice (ci_local = l16)
            float* hp = &h3q[node_l * 132 + l16 * 8];
            *(float4*)(hp)     = make_float4(hq8[0], hq8[1], hq8[2], hq8[3]);
            *(float4*)(hp + 4) = make_float4(hq8[4], hq8[5], hq8[6], hq8[7]);
        }
        // stage quarter-q conv3 weights (w2a: [o(128)][192])
#pragma unroll 1
        for (int i = tid; i < 1536; i += 256) {
            int unit = i / 3, p = i - unit * 3;
            int c4 = unit >> 7, o = unit & 127;
            float4 v = *(const float4*)&w2a[o * 192 + (q * 16 + c4 * 4) * 3 + p * 4];
            *(float4*)&wbuf[c4 * 1536 + o * 12 + p * 4] = v;
        }
        __syncthreads();

#pragma unroll 1
        for (int c4 = 0; c4 < 4; ++c4) {
            float hv[4][8];
#pragma unroll
            for (int i = 0; i < 4; ++i) {
                const float* hp = &h3q[node_l * 132 + (c4 * 4 + i) * 8];
                float4 v0 = *(const float4*)(hp);
                float4 v1 = *(const float4*)(hp + 4);
                hv[i][0] = v0.x; hv[i][1] = v0.y; hv[i][2] = v0.z; hv[i][3] = v0.w;
                hv[i][4] = v1.x; hv[i][5] = v1.y; hv[i][6] = v1.z; hv[i][7] = v1.w;
            }
#pragma unroll
            for (int j = 0; j < 8; ++j) {
                const int o = (j < 4) ? (l16 + 16 * j) : (64 + l16 + 16 * (j - 4));
                const float* wp = &wbuf[c4 * 1536 + o * 12];
                float4 w0 = *(const float4*)(wp);
                float4 w1 = *(const float4*)(wp + 4);
                float4 w2 = *(const float4*)(wp + 8);
                float wr[12];
                wr[0] = w0.x; wr[1] = w0.y; wr[2]  = w0.z; wr[3]  = w0.w;
                wr[4] = w1.x; wr[5] = w1.y; wr[6]  = w1.z; wr[7]  = w1.w;
                wr[8] = w2.x; wr[9] = w2.y; wr[10] = w2.z; wr[11] = w2.w;
#pragma unroll
                for (int i = 0; i < 4; ++i)
#pragma unroll
                    for (int k = 0; k < 3; ++k)
#pragma unroll
                        for (int t = 0; t < 6; ++t)
                            acc3[j][t] = fmaf(wr[i * 3 + k], hv[i][t + k], acc3[j][t]);
            }
        }
    }

    // ---------------- GLU + projection 64->16 ----------------
    float h4r[4][6];
#pragma unroll
    for (int j = 0; j < 4; ++j)
#pragma unroll
        for (int t = 0; t < 6; ++t)
            h4r[j][t] = acc3[j][t] * sigf(acc3[j + 4][t]);

    float pacc[6] = {0.f, 0.f, 0.f, 0.f, 0.f, 0.f};

#pragma unroll 1
    for (int q = 0; q < 4; ++q) {
        float hq[6];
#pragma unroll
        for (int j = 0; j < 4; ++j)
            if (q == j) {
#pragma unroll
                for (int t = 0; t < 6; ++t) hq[t] = h4r[j][t];
            }

        __syncthreads();  // prior proj / conv3 reads done
        {
            float* hp = &h3q[node_l * 132 + l16 * 8];
            *(float4*)(hp)     = make_float4(hq[0], hq[1], hq[2], hq[3]);
            *(float2*)(hp + 4) = make_float2(hq[4], hq[5]);
        }
        __syncthreads();

        float4 wv0 = *(const float4*)&W2T[l16 * 64 + q * 16 + 0];
        float4 wv1 = *(const float4*)&W2T[l16 * 64 + q * 16 + 4];
        float4 wv2 = *(const float4*)&W2T[l16 * 64 + q * 16 + 8];
        float4 wv3 = *(const float4*)&W2T[l16 * 64 + q * 16 + 12];
        float wq[16];
        wq[0]  = wv0.x; wq[1]  = wv0.y; wq[2]  = wv0.z; wq[3]  = wv0.w;
        wq[4]  = wv1.x; wq[5]  = wv1.y; wq[6]  = wv1.z; wq[7]  = wv1.w;
        wq[8]  = wv2.x; wq[9]  = wv2.y; wq[10] = wv2.z; wq[11] = wv2.w;
        wq[12] = wv3.x; wq[13] = wv3.y; wq[14] = wv3.z; wq[15] = wv3.w;

#pragma unroll
        for (int cl = 0; cl < 16; ++cl) {
            const float* ap = &h3q[node_l * 132 + cl * 8];
            float4 a0 = *(const float4*)(ap);
            float2 a1 = *(const float2*)(ap + 4);
            pacc[0] = fmaf(wq[cl], a0.x, pacc[0]);
            pacc[1] = fmaf(wq[cl], a0.y, pacc[1]);
            pacc[2] = fmaf(wq[cl], a0.z, pacc[2]);
            pacc[3] = fmaf(wq[cl], a0.w, pacc[3]);
            pacc[4] = fmaf(wq[cl], a1.x, pacc[4]);
            pacc[5] = fmaf(wq[cl], a1.y, pacc[5]);
        }
    }

    const int node = base + node_l;
#pragma unroll
    for (int t = 0; t < 6; ++t)
        xw2[(size_t)node * 96 + t * 16 + l16] = pacc[t];
}

// ---- counts per graph (batch sorted) --------------------------------------
__global__ void k_counts(const int* __restrict__ batch, float* __restrict__ cnt,
                         int n, int ngraphs)
{
    int g = threadIdx.x;
    if (g >= ngraphs) return;
    int lo = 0, hi = n;
    while (lo < hi) { int m = (lo + hi) >> 1; if (batch[m] < g) lo = m + 1; else hi = m; }
    int lo2 = 0, hi2 = n;
    while (lo2 < hi2) { int m = (lo2 + hi2) >> 1; if (batch[m] < g + 1) lo2 = m + 1; else hi2 = m; }
    cnt[g] = (float)(lo2 - lo);
}

// ---- mean-pool numerator ---------------------------------------------------
__global__ __launch_bounds__(128) void k_pool(
    const float* __restrict__ h5, const int* __restrict__ batch,
    float* __restrict__ pool, int nNodes)
{
    int j = threadIdx.x;
    if (j >= 96) return;
    int n0 = blockIdx.x * 64;
    int n1 = min(n0 + 64, nNodes);
    int cur = batch[n0];
    float acc = 0.f;
    for (int n = n0; n < n1; ++n) {
        int g = batch[n];
        if (g != cur) { atomicAdd(&pool[cur * 96 + j], acc); acc = 0.f; cur = g; }
        acc += h5[(size_t)n * 96 + j];
    }
    atomicAdd(&pool[cur * 96 + j], acc);
}

// ---- final conv_glu: (16,16,6) -> (16,64,4) --------------------------------
__global__ __launch_bounds__(256) void k_final(
    const float* __restrict__ pool, const float* __restrict__ cnt,
    const float* __restrict__ w, const float* __restrict__ b,
    float* __restrict__ out)
{
    __shared__ float m[96];
    __shared__ float ws[6144];
    __shared__ float bs[128];
    int g = blockIdx.x, tid = threadIdx.x;
    if (tid < 96) m[tid] = pool[g * 96 + tid] / fmaxf(cnt[g], 1.0f);
    for (int i = tid; i < 6144; i += 256) ws[i] = w[i];
    if (tid < 128) bs[tid] = b[tid];
    __syncthreads();

    int c = tid >> 2, t = tid & 3;
    float a = bs[c], gg = bs[c + 64];
#pragma unroll
    for (int ci = 0; ci < 16; ++ci)
#pragma unroll
        for (int k = 0; k < 3; ++k) {
            float xv = m[(t + k) * 16 + ci];
            a  = fmaf(ws[c * 48 + ci * 3 + k],        xv, a);
            gg = fmaf(ws[(c + 64) * 48 + ci * 3 + k], xv, gg);
        }
    out[g * 256 + c * 4 + t] = a * sigf(gg);
}

// ---------------------------------------------------------------------------
extern "C" void kernel_launch(void* const* d_in, const int* in_sizes, int n_in,
                              void* d_out, int out_size, void* d_ws, size_t ws_size,
                              hipStream_t stream)
{
    const float* x      = (const float*)d_in[0];
    const int*   ei     = (const int*)  d_in[1];
    const int*   batch  = (const int*)  d_in[2];
    const float* w_t1a  = (const float*)d_in[3];
    const float* b_t1a  = (const float*)d_in[4];
    const float* w_s1   = (const float*)d_in[5];
    const float* bb_s1  = (const float*)d_in[6];
    const float* w_t1b  = (const float*)d_in[7];
    const float* b_t1b  = (const float*)d_in[8];
    const float* w_t2a  = (const float*)d_in[9];
    const float* b_t2a  = (const float*)d_in[10];
    const float* w_s2   = (const float*)d_in[11];
    const float* bb_s2  = (const float*)d_in[12];
    const float* w_t2b  = (const float*)d_in[13];
    const float* b_t2b  = (const float*)d_in[14];
    float* out = (float*)d_out;

    const int* row = ei;
    const int* col = ei + NE;

    float* wsp  = (float*)d_ws;
    float* dinv = wsp;                     // N
    float* deg  = dinv + NN;               // N
    float* pool = deg  + NN;               // 16*96
    float* cnt  = pool + NG * 96;          // 16
    float* xw   = cnt  + NG;               // N*160 (xw1; later xw2 uses N*96)
    float* agg  = xw   + (size_t)NN * 160; // N*160 (agg1/h2; later agg2/h5 N*96)

    hipMemsetAsync(agg,  0, (size_t)NN * 160 * sizeof(float), stream);
    hipMemsetAsync(deg,  0, (size_t)NN * sizeof(float), stream);
    hipMemsetAsync(pool, 0, (size_t)NG * 96 * sizeof(float), stream);

    k_deg <<<(NE + 255) / 256, 256, 0, stream>>>(col, deg, NE);
    k_dinv<<<(NN + 255) / 256, 256, 0, stream>>>(deg, dinv, NN);

    k_conv1_proj<<<(NN * 10 + 255) / 256, 256, 0, stream>>>(
        x, w_t1a, b_t1a, w_s1, xw, NN);

    k_scatter<160><<<(NE * 64) / 256, 256, 0, stream>>>(xw, row, col, dinv, agg, NE);
    k_gcn_finish<160><<<((NN * 160) + 255) / 256, 256, 0, stream>>>(
        agg, xw, dinv, bb_s1, NN * 160);

    k_conv23_v2<<<NN / 16, 256, 0, stream>>>(
        agg, w_t1b, b_t1b, w_t2a, b_t2a, w_s2, xw);

    hipMemsetAsync(agg, 0, (size_t)NN * 96 * sizeof(float), stream);

    k_scatter<96><<<(NE * 64) / 256, 256, 0, stream>>>(xw, row, col, dinv, agg, NE);
    k_gcn_finish<96><<<((NN * 96) + 255) / 256, 256, 0, stream>>>(
        agg, xw, dinv, bb_s2, NN * 96);

    k_counts<<<1, 64, 0, stream>>>(batch, cnt, NN, NG);
    k_pool<<<(NN + 63) / 64, 128, 0, stream>>>(agg, batch, pool, NN);

    k_final<<<NG, 256, 0, stream>>>(pool, cnt, w_t2b, b_t2b, out);
}

// Round 4
// 511.878 us; speedup vs baseline: 2.3367x; 1.9374x over previous
//
#include <hip/hip_runtime.h>
#include <hip/hip_bf16.h>

// ---------------------------------------------------------------------------
// STGCN fused pipeline, round 4.
//  - GCN via bucketed GATHER (no fp32 atomics, no agg memsets, deg from bucket)
//  - dinv pre-folded into xw at producers (conv1 / conv23 epilogues)
//  - conv23 v3: 64-thread blocks (1 wave, 2 nodes), ZERO barriers, weights from
//    global (pre-packed lane-contiguous float4), tiny LDS for transposes only.
// ---------------------------------------------------------------------------

#define NN 50000
#define NE 500000
#define NG 16
#define CAP 64   // per-node incoming-edge capacity (Poisson(10): max ~32)

__device__ __forceinline__ float sigf(float g) {
    return 1.0f / (1.0f + __expf(-g));
}

// ---- bucket build: cnt[c]++ and store src id ------------------------------
__global__ void k_fill(const int* __restrict__ row, const int* __restrict__ col,
                       int* __restrict__ cnt, unsigned short* __restrict__ bucket,
                       int E)
{
    int e = blockIdx.x * 256 + threadIdx.x;
    if (e >= E) return;
    int c = col[e];
    int pos = atomicAdd(&cnt[c], 1);
    if (pos < CAP) bucket[(size_t)c * CAP + pos] = (unsigned short)row[e];
}

__global__ void k_dinv(const int* __restrict__ cnt, float* __restrict__ dinv, int n) {
    int i = blockIdx.x * 256 + threadIdx.x;
    if (i < n) dinv[i] = rsqrtf((float)cnt[i] + 1.0f);
}

// ---- weight repack into lane-contiguous float4 layouts --------------------
// p2: conv2 (w_t1b 128x48):  [c4(4)][j(4)][kv(3)][l32(32)] float4
// p3: conv3 (w_t2a 128x192): [q(4)][c4(4)][j(4)][kv(3)][l32(32)] float4
// pw: proj  (w_s2 64x16):    [q(4)][cl4(4)][l16(16)] float4 (components = cl)
// o(j,l32) = (j&1)*32 + l32 + (j>>1)*64   (j0:a co=l32, j1:a co=l32+32, j2/3: g)
__global__ void k_prep(const float* __restrict__ w1b, const float* __restrict__ w2a,
                       const float* __restrict__ ws2,
                       float4* __restrict__ p2, float4* __restrict__ p3,
                       float4* __restrict__ pw)
{
    int i = blockIdx.x * 256 + threadIdx.x;
    if (i < 1536) {
        int l32 = i & 31; int r = i >> 5;
        int kv = r % 3; r /= 3;
        int j = r & 3; int c4 = r >> 2;
        int o = (j & 1) * 32 + l32 + (j >> 1) * 64;
        p2[i] = *(const float4*)&w1b[o * 48 + c4 * 12 + kv * 4];
    }
    if (i < 6144) {
        int l32 = i & 31; int r = i >> 5;
        int kv = r % 3; r /= 3;
        int j = r & 3; int c4q = r >> 2;
        int c4 = c4q & 3; int q = c4q >> 2;
        int o = (j & 1) * 32 + l32 + (j >> 1) * 64;
        p3[i] = *(const float4*)&w2a[o * 192 + (q * 16 + c4 * 4) * 3 + kv * 4];
    }
    if (i < 256) {
        int l16 = i & 15; int r = i >> 4;
        int cl4 = r & 3; int q = r >> 2;
        float4 v;
        v.x = ws2[(q * 16 + cl4 * 4 + 0) * 16 + l16];
        v.y = ws2[(q * 16 + cl4 * 4 + 1) * 16 + l16];
        v.z = ws2[(q * 16 + cl4 * 4 + 2) * 16 + l16];
        v.w = ws2[(q * 16 + cl4 * 4 + 3) * 16 + l16];
        pw[i] = v;
    }
}

// ---- conv_glu1 (2->64, 12->10) + proj 64->16, output pre-scaled by dinv ---
__global__ __launch_bounds__(256) void k_conv1_proj(
    const float* __restrict__ x, const float* __restrict__ w,
    const float* __restrict__ b, const float* __restrict__ W1,
    const float* __restrict__ dinv, float* __restrict__ xw1, int nNodes)
{
    __shared__ float ws[768];
    __shared__ float bs[128];
    __shared__ float W1s[1024];
    int tid = threadIdx.x;
    for (int i = tid; i < 768;  i += 256) ws[i]  = w[i];
    for (int i = tid; i < 1024; i += 256) W1s[i] = W1[i];
    if (tid < 128) bs[tid] = b[tid];
    __syncthreads();

    int idx = blockIdx.x * 256 + tid;
    if (idx >= nNodes * 10) return;
    int n = idx / 10, t = idx % 10;

    float xr[6];
#pragma unroll
    for (int ci = 0; ci < 2; ++ci)
#pragma unroll
        for (int k = 0; k < 3; ++k)
            xr[ci * 3 + k] = x[n * 24 + ci * 12 + t + k];

    float acc[16];
#pragma unroll
    for (int d = 0; d < 16; ++d) acc[d] = 0.f;

    for (int c = 0; c < 64; ++c) {
        float a = bs[c], g = bs[c + 64];
#pragma unroll
        for (int j = 0; j < 6; ++j) {
            a = fmaf(ws[c * 6 + j],        xr[j], a);
            g = fmaf(ws[(c + 64) * 6 + j], xr[j], g);
        }
        float h = a * sigf(g);
#pragma unroll
        for (int d = 0; d < 16; ++d) acc[d] = fmaf(W1s[c * 16 + d], h, acc[d]);
    }
    float dv = dinv[n];
    float* o = &xw1[n * 160 + t * 16];
#pragma unroll
    for (int d = 0; d < 16; ++d) o[d] = acc[d] * dv;
}

// ---- GCN gather: h[c] = relu(dinv[c]*(sum_r xs[r] + xs[c]) + bias) --------
// wave per node; incoming src ids preloaded into lanes, broadcast via shfl.
template <int W>
__global__ __launch_bounds__(256) void k_gather(
    const float* __restrict__ xs, const unsigned short* __restrict__ bucket,
    const int* __restrict__ cnt, const float* __restrict__ dinv,
    const float* __restrict__ bias, float* __restrict__ h, int nNodes)
{
    int wid  = (blockIdx.x * 256 + threadIdx.x) >> 6;
    int lane = threadIdx.x & 63;
    if (wid >= nNodes) return;
    const int c = wid;
    const int deg = min(cnt[c], CAP);

    int myid = 0;
    if (lane < deg) myid = (int)bucket[(size_t)c * CAP + lane];

    float a0 = 0.f, a1 = 0.f, a2 = 0.f;
    for (int j = 0; j < deg; ++j) {
        int r = __shfl(myid, j);
        const float* p = xs + (size_t)r * W;
        a0 += p[lane];
        if (W == 160) {
            a1 += p[lane + 64];
            if (lane < 32) a2 += p[lane + 128];
        } else {
            if (lane < 32) a1 += p[lane + 64];
        }
    }

    const float dv = dinv[c];
    const float* ps = xs + (size_t)c * W;
    float* ho = h + (size_t)c * W;
    ho[lane] = fmaxf(dv * (a0 + ps[lane]) + bias[lane & 15], 0.f);
    if (W == 160) {
        ho[lane + 64] = fmaxf(dv * (a1 + ps[lane + 64]) + bias[lane & 15], 0.f);
        if (lane < 32)
            ho[lane + 128] = fmaxf(dv * (a2 + ps[lane + 128]) + bias[lane & 15], 0.f);
    } else {
        if (lane < 32)
            ho[lane + 64] = fmaxf(dv * (a1 + ps[lane + 64]) + bias[lane & 15], 0.f);
    }
}

// ---------------------------------------------------------------------------
// conv_glu2 (16->64,10->8) + conv_glu3 (64->64,8->6) + proj 64->16, v3.
// 1 wave / block, 2 nodes / wave (32-lane subgroups). No barriers.
// Lane l32 owns co = l32 and co = l32+32 (a and g halves -> acc[4][..]).
// Weights from global packed float4 (L1/L2-hot). Output pre-scaled by dinv.
// ---------------------------------------------------------------------------
__global__ __launch_bounds__(64, 4) void k_conv23_v3(
    const float* __restrict__ h2g, const float4* __restrict__ p2,
    const float* __restrict__ b1b, const float4* __restrict__ p3,
    const float* __restrict__ b2a, const float4* __restrict__ pw,
    const float* __restrict__ dinv, float* __restrict__ xw2)
{
    __shared__ float h2s[2 * 196];  // [node2][ci16][t pad12]
    __shared__ float h3q[2 * 132];  // quarter buf [node2][ci_l16][t pad8]

    const int tid  = threadIdx.x;
    const int l32  = tid & 31;
    const int nl   = tid >> 5;            // 0..1
    const int base = blockIdx.x * 2;      // grid = NN/2
    const int node = base + nl;

    // ---- stage h2 (2 nodes x 160 floats), transposed to [ci][t] ----
#pragma unroll
    for (int it = 0; it < 2; ++it) {
        int i = tid + it * 64;
        if (i < 80) {
            int ns = i / 40, r4 = i - ns * 40;
            int t = r4 >> 2, ci0 = (r4 & 3) << 2;
            float4 v = *(const float4*)&h2g[(size_t)(base + ns) * 160 + t * 16 + ci0];
            float* hp = &h2s[ns * 196 + ci0 * 12 + t];
            hp[0]  = v.x;
            hp[12] = v.y;
            hp[24] = v.z;
            hp[36] = v.w;
        }
    }

    // ---- conv2: (16,10) -> (64+64, 8) ----
    float acc[4][8];
    {
        float b0 = b1b[l32], b1 = b1b[l32 + 32], b2 = b1b[64 + l32], b3 = b1b[96 + l32];
#pragma unroll
        for (int t = 0; t < 8; ++t) { acc[0][t] = b0; acc[1][t] = b1; acc[2][t] = b2; acc[3][t] = b3; }
    }

#pragma unroll 1
    for (int c4 = 0; c4 < 4; ++c4) {
        float hv[4][12];
#pragma unroll
        for (int i = 0; i < 4; ++i) {
            const float* hp = &h2s[nl * 196 + (c4 * 4 + i) * 12];
            float4 v0 = *(const float4*)(hp);
            float4 v1 = *(const float4*)(hp + 4);
            float4 v2 = *(const float4*)(hp + 8);
            hv[i][0] = v0.x; hv[i][1] = v0.y; hv[i][2]  = v0.z; hv[i][3]  = v0.w;
            hv[i][4] = v1.x; hv[i][5] = v1.y; hv[i][6]  = v1.z; hv[i][7]  = v1.w;
            hv[i][8] = v2.x; hv[i][9] = v2.y; hv[i][10] = v2.z; hv[i][11] = v2.w;
        }
#pragma unroll
        for (int j = 0; j < 4; ++j) {
            float4 w0 = p2[((c4 * 4 + j) * 3 + 0) * 32 + l32];
            float4 w1 = p2[((c4 * 4 + j) * 3 + 1) * 32 + l32];
            float4 w2 = p2[((c4 * 4 + j) * 3 + 2) * 32 + l32];
            float wr[12];
            wr[0] = w0.x; wr[1] = w0.y; wr[2]  = w0.z; wr[3]  = w0.w;
            wr[4] = w1.x; wr[5] = w1.y; wr[6]  = w1.z; wr[7]  = w1.w;
            wr[8] = w2.x; wr[9] = w2.y; wr[10] = w2.z; wr[11] = w2.w;
#pragma unroll
            for (int i = 0; i < 4; ++i)
#pragma unroll
                for (int k = 0; k < 3; ++k)
#pragma unroll
                    for (int t = 0; t < 8; ++t)
                        acc[j][t] = fmaf(wr[i * 3 + k], hv[i][t + k], acc[j][t]);
        }
    }

    float h3r[2][8];
#pragma unroll
    for (int t = 0; t < 8; ++t) {
        h3r[0][t] = acc[0][t] * sigf(acc[2][t]);
        h3r[1][t] = acc[1][t] * sigf(acc[3][t]);
    }

    // ---- conv3: (64,8) -> (64+64, 6), quarter-streamed through h3q ----
    float c3[4][6];
    {
        float b0 = b2a[l32], b1 = b2a[l32 + 32], b2 = b2a[64 + l32], b3 = b2a[96 + l32];
#pragma unroll
        for (int t = 0; t < 6; ++t) { c3[0][t] = b0; c3[1][t] = b1; c3[2][t] = b2; c3[3][t] = b3; }
    }

#pragma unroll 1
    for (int q = 0; q < 4; ++q) {
        // write quarter q: rows ci_l = l32&15 from owning 16 lanes per subgroup
        const int srcA = (q < 2);
        const int own  = srcA ? ((l32 >> 4) == q) : ((l32 >> 4) == (q - 2));
        float v[8];
#pragma unroll
        for (int t = 0; t < 8; ++t) v[t] = srcA ? h3r[0][t] : h3r[1][t];
        if (own) {
            float* hp = &h3q[nl * 132 + (l32 & 15) * 8];
            *(float4*)(hp)     = make_float4(v[0], v[1], v[2], v[3]);
            *(float4*)(hp + 4) = make_float4(v[4], v[5], v[6], v[7]);
        }
#pragma unroll 1
        for (int c4 = 0; c4 < 4; ++c4) {
            float hv[4][8];
#pragma unroll
            for (int i = 0; i < 4; ++i) {
                const float* hp = &h3q[nl * 132 + (c4 * 4 + i) * 8];
                float4 v0 = *(const float4*)(hp);
                float4 v1 = *(const float4*)(hp + 4);
                hv[i][0] = v0.x; hv[i][1] = v0.y; hv[i][2] = v0.z; hv[i][3] = v0.w;
                hv[i][4] = v1.x; hv[i][5] = v1.y; hv[i][6] = v1.z; hv[i][7] = v1.w;
            }
#pragma unroll
            for (int j = 0; j < 4; ++j) {
                float4 w0 = p3[(((q * 4 + c4) * 4 + j) * 3 + 0) * 32 + l32];
                float4 w1 = p3[(((q * 4 + c4) * 4 + j) * 3 + 1) * 32 + l32];
                float4 w2 = p3[(((q * 4 + c4) * 4 + j) * 3 + 2) * 32 + l32];
                float wr[12];
                wr[0] = w0.x; wr[1] = w0.y; wr[2]  = w0.z; wr[3]  = w0.w;
                wr[4] = w1.x; wr[5] = w1.y; wr[6]  = w1.z; wr[7]  = w1.w;
                wr[8] = w2.x; wr[9] = w2.y; wr[10] = w2.z; wr[11] = w2.w;
#pragma unroll
                for (int i = 0; i < 4; ++i)
#pragma unroll
                    for (int k = 0; k < 3; ++k)
#pragma unroll
                        for (int t = 0; t < 6; ++t)
                            c3[j][t] = fmaf(wr[i * 3 + k], hv[i][t + k], c3[j][t]);
            }
        }
    }

    // ---- GLU + proj 64->16 (pre-scaled by dinv) ----
    float h4[2][6];
#pragma unroll
    for (int t = 0; t < 6; ++t) {
        h4[0][t] = c3[0][t] * sigf(c3[2][t]);
        h4[1][t] = c3[1][t] * sigf(c3[3][t]);
    }

    float pacc[3] = {0.f, 0.f, 0.f};
    const int d  = l32 & 15;
    const int th = l32 >> 4;   // 0: t=0..2, 1: t=3..5

#pragma unroll 1
    for (int q = 0; q < 4; ++q) {
        const int srcA = (q < 2);
        const int own  = srcA ? ((l32 >> 4) == q) : ((l32 >> 4) == (q - 2));
        float v[6];
#pragma unroll
        for (int t = 0; t < 6; ++t) v[t] = srcA ? h4[0][t] : h4[1][t];
        if (own) {
            float* hp = &h3q[nl * 132 + (l32 & 15) * 8];
            *(float4*)(hp)     = make_float4(v[0], v[1], v[2], v[3]);
            *(float2*)(hp + 4) = make_float2(v[4], v[5]);
        }
        float4 wv0 = pw[(q * 4 + 0) * 16 + d];
        float4 wv1 = pw[(q * 4 + 1) * 16 + d];
        float4 wv2 = pw[(q * 4 + 2) * 16 + d];
        float4 wv3 = pw[(q * 4 + 3) * 16 + d];
        float wq[16];
        wq[0]  = wv0.x; wq[1]  = wv0.y; wq[2]  = wv0.z; wq[3]  = wv0.w;
        wq[4]  = wv1.x; wq[5]  = wv1.y; wq[6]  = wv1.z; wq[7]  = wv1.w;
        wq[8]  = wv2.x; wq[9]  = wv2.y; wq[10] = wv2.z; wq[11] = wv2.w;
        wq[12] = wv3.x; wq[13] = wv3.y; wq[14] = wv3.z; wq[15] = wv3.w;
#pragma unroll
        for (int cl = 0; cl < 16; ++cl) {
            const float* hp = &h3q[nl * 132 + cl * 8];
            float4 e0 = *(const float4*)(hp);
            float2 e1 = *(const float2*)(hp + 4);
            float s0 = th ? e0.w : e0.x;
            float s1 = th ? e1.x : e0.y;
            float s2 = th ? e1.y : e0.z;
            pacc[0] = fmaf(wq[cl], s0, pacc[0]);
            pacc[1] = fmaf(wq[cl], s1, pacc[1]);
            pacc[2] = fmaf(wq[cl], s2, pacc[2]);
        }
    }

    const float dv = dinv[node];
#pragma unroll
    for (int s = 0; s < 3; ++s)
        xw2[(size_t)node * 96 + (th * 3 + s) * 16 + d] = pacc[s] * dv;
}

// ---- counts per graph via binary search (batch sorted) --------------------
__global__ void k_counts(const int* __restrict__ batch, float* __restrict__ cnt,
                         int n, int ngraphs)
{
    int g = threadIdx.x;
    if (g >= ngraphs) return;
    int lo = 0, hi = n;
    while (lo < hi) { int m = (lo + hi) >> 1; if (batch[m] < g) lo = m + 1; else hi = m; }
    int lo2 = 0, hi2 = n;
    while (lo2 < hi2) { int m = (lo2 + hi2) >> 1; if (batch[m] < g + 1) lo2 = m + 1; else hi2 = m; }
    cnt[g] = (float)(lo2 - lo);
}

// ---- mean-pool numerator (batch sorted, run-length) -----------------------
__global__ __launch_bounds__(128) void k_pool(
    const float* __restrict__ h5, const int* __restrict__ batch,
    float* __restrict__ pool, int nNodes)
{
    int j = threadIdx.x;
    if (j >= 96) return;
    int n0 = blockIdx.x * 64;
    int n1 = min(n0 + 64, nNodes);
    int cur = batch[n0];
    float acc = 0.f;
    for (int n = n0; n < n1; ++n) {
        int g = batch[n];
        if (g != cur) { atomicAdd(&pool[cur * 96 + j], acc); acc = 0.f; cur = g; }
        acc += h5[(size_t)n * 96 + j];
    }
    atomicAdd(&pool[cur * 96 + j], acc);
}

// ---- final conv_glu: (16,16,6) -> (16,64,4) -------------------------------
__global__ __launch_bounds__(256) void k_final(
    const float* __restrict__ pool, const float* __restrict__ cnt,
    const float* __restrict__ w, const float* __restrict__ b,
    float* __restrict__ out)
{
    __shared__ float m[96];
    __shared__ float ws[6144];
    __shared__ float bs[128];
    int g = blockIdx.x, tid = threadIdx.x;
    if (tid < 96) m[tid] = pool[g * 96 + tid] / fmaxf(cnt[g], 1.0f);
    for (int i = tid; i < 6144; i += 256) ws[i] = w[i];
    if (tid < 128) bs[tid] = b[tid];
    __syncthreads();

    int c = tid >> 2, t = tid & 3;
    float a = bs[c], gg = bs[c + 64];
#pragma unroll
    for (int ci = 0; ci < 16; ++ci)
#pragma unroll
        for (int k = 0; k < 3; ++k) {
            float xv = m[(t + k) * 16 + ci];
            a  = fmaf(ws[c * 48 + ci * 3 + k],        xv, a);
            gg = fmaf(ws[(c + 64) * 48 + ci * 3 + k], xv, gg);
        }
    out[g * 256 + c * 4 + t] = a * sigf(gg);
}

// ---------------------------------------------------------------------------
extern "C" void kernel_launch(void* const* d_in, const int* in_sizes, int n_in,
                              void* d_out, int out_size, void* d_ws, size_t ws_size,
                              hipStream_t stream)
{
    const float* x      = (const float*)d_in[0];
    const int*   ei     = (const int*)  d_in[1];
    const int*   batch  = (const int*)  d_in[2];
    const float* w_t1a  = (const float*)d_in[3];
    const float* b_t1a  = (const float*)d_in[4];
    const float* w_s1   = (const float*)d_in[5];
    const float* bb_s1  = (const float*)d_in[6];
    const float* w_t1b  = (const float*)d_in[7];
    const float* b_t1b  = (const float*)d_in[8];
    const float* w_t2a  = (const float*)d_in[9];
    const float* b_t2a  = (const float*)d_in[10];
    const float* w_s2   = (const float*)d_in[11];
    const float* bb_s2  = (const float*)d_in[12];
    const float* w_t2b  = (const float*)d_in[13];
    const float* b_t2b  = (const float*)d_in[14];
    float* out = (float*)d_out;

    const int* row = ei;
    const int* col = ei + NE;

    // workspace layout (~71 MB)
    float* F    = (float*)d_ws;
    float* xw   = F;                         // NN*160 (xw1 scaled; later xw2 N*96)
    float* h    = xw + (size_t)NN * 160;     // NN*160 (h2; later h5 N*96)
    float* p2f  = h  + (size_t)NN * 160;     // 6144
    float* p3f  = p2f + 6144;                // 24576
    float* pwf  = p3f + 24576;               // 1024
    float* dinv = pwf + 1024;                // NN
    float* pool = dinv + NN;                 // NG*96
    float* gcnt = pool + NG * 96;            // NG
    int*   cnt  = (int*)(gcnt + NG);         // NN ints
    unsigned short* bucket = (unsigned short*)(cnt + NN); // NN*CAP ushort

    hipMemsetAsync(cnt,  0, (size_t)NN * sizeof(int), stream);
    hipMemsetAsync(pool, 0, (size_t)NG * 96 * sizeof(float), stream);

    // CSR-ish bucket build + dinv + weight repack
    k_fill<<<(NE + 255) / 256, 256, 0, stream>>>(row, col, cnt, bucket, NE);
    k_dinv<<<(NN + 255) / 256, 256, 0, stream>>>(cnt, dinv, NN);
    k_prep<<<24, 256, 0, stream>>>(w_t1b, w_t2a, w_s2,
                                   (float4*)p2f, (float4*)p3f, (float4*)pwf);

    // stage 1: conv_glu1 + proj (scaled by dinv)
    k_conv1_proj<<<(NN * 10 + 255) / 256, 256, 0, stream>>>(
        x, w_t1a, b_t1a, w_s1, dinv, xw, NN);

    // GCN 1 (gather, fused epilogue)
    k_gather<160><<<(NN * 64) / 256, 256, 0, stream>>>(
        xw, bucket, cnt, dinv, bb_s1, h, NN);

    // stage 2: conv_glu2 + conv_glu3 + proj (scaled by dinv)
    k_conv23_v3<<<NN / 2, 64, 0, stream>>>(
        h, (const float4*)p2f, b_t1b, (const float4*)p3f, b_t2a,
        (const float4*)pwf, dinv, xw);

    // GCN 2 (gather, fused epilogue)
    k_gather<96><<<(NN * 64) / 256, 256, 0, stream>>>(
        xw, bucket, cnt, dinv, bb_s2, h, NN);

    // pooling + final conv_glu
    k_counts<<<1, 64, 0, stream>>>(batch, gcnt, NN, NG);
    k_pool<<<(NN + 63) / 64, 128, 0, stream>>>(h, batch, pool, NN);
    k_final<<<NG, 256, 0, stream>>>(pool, gcnt, w_t2b, b_t2b, out);
}